// Round 10
// baseline (365.317 us; speedup 1.0000x reference)
//
#include <hip/hip_runtime.h>
#include <hip/hip_bf16.h>

// GCN 2-layer, counting-sort CSR + bf16-plane gather aggregation.
// N=100000, F_in=512, H=16, C=40, E=3200000.
//
// Algebra: with hs = dinv*h pre-scaled at the producer,
//   (A_hat h)[i] = dinv[i] * ( sum_{s in N(i)} hs[s] + hs[i] ).
// Layer2 aggregate-then-transform: A_hat(h2 W2) == (A_hat h2) W2.
//
// R10 structure:
//   memset cnt; k_cnthist (bucket histT + per-node cnt in one dst pass)
//   k_scanrow (histT column scan -> histS, keeps histT; + dinv = rsqrt(cnt+1))
//   k_scanbkt (bucket bases)
//   k_fat     (PARTITION blocks ∥ GEMM1 blocks, 2:1 interleaved — BW-bound
//              GEMM1 overlaps latency/LDS-bound partition on the same grid;
//              partition rebuilds local bases from its histT row instead of
//              re-histogramming 4096 edges)
//   k_part2   (exact per-node sort within bucket -> ssrc, rs)
//   k_gagg1   (layer-1 gather, bf16 32B rows, L2-resident table)
//   k_gagg2f  (layer-2 gather fused with GEMM2 + bias)
// All global IO coalesced by construction (random 4B scatters amplify HBM
// writes 10-15x; measured R3/R5/R6).

#define TPB 256
#define PCH 4096            // edges per partition chunk
#define NBKT_MAX 392        // buckets (100000>>8 = 391) padded
#define MAXB 10240          // max edges per bucket staged in LDS (avg 8184)

typedef unsigned int u32;
typedef float __attribute__((ext_vector_type(4))) f32x4;

__device__ __forceinline__ float bflo(u32 u) { return __uint_as_float(u << 16); }
__device__ __forceinline__ float bfhi(u32 u) { return __uint_as_float(u & 0xFFFF0000u); }
__device__ __forceinline__ unsigned short f2bf(float f) {
    __hip_bfloat16 h = __float2bfloat16(f);
    return *reinterpret_cast<unsigned short*>(&h);
}

// ---------------------------------------------------------------- bucket histogram + per-node degree
__global__ __launch_bounds__(TPB) void k_cnthist(const int* __restrict__ dst,
                                                 int* __restrict__ cnt,
                                                 int* __restrict__ histT,
                                                 int E, int nbkt) {
    __shared__ int hist[NBKT_MAX];
    const int tid = threadIdx.x, blk = blockIdx.x;
    for (int k = tid; k < NBKT_MAX; k += TPB) hist[k] = 0;
    __syncthreads();
    const int base = blk * PCH;
    const int m = min(PCH, E - base);
    for (int i = tid; i < m; i += TPB) {
        int d = dst[base + i];
        atomicAdd(&hist[d >> 8], 1);
        atomicAdd(&cnt[d], 1);
    }
    __syncthreads();
    for (int k = tid; k < nbkt; k += TPB) histT[blk * NBKT_MAX + k] = hist[k];
}

// ---------------------------------------------------------------- scan bucket rows across blocks (histT kept raw)
__global__ __launch_bounds__(512) void k_scanrow(const int* __restrict__ histT,
                                                 int* __restrict__ histS,
                                                 int* __restrict__ rowtot,
                                                 const int* __restrict__ cnt,
                                                 float* __restrict__ dinv,
                                                 int NP, int n) {
    __shared__ int s[1024];
    const int t = threadIdx.x, k = blockIdx.x;
    if (t < 256) {                          // fused dinv for this bucket's nodes
        int node = (k << 8) + t;
        if (node < n) dinv[node] = rsqrtf((float)(cnt[node] + 1));
    }
    int v0 = (t < NP) ? histT[t * NBKT_MAX + k] : 0;
    int v1 = (t + 512 < NP) ? histT[(t + 512) * NBKT_MAX + k] : 0;
    s[t] = v0; s[t + 512] = v1;
    __syncthreads();
    for (int off = 1; off <= 512; off <<= 1) {
        int a0 = (t >= off) ? s[t - off] : 0;
        int a1 = s[t + 512 - off];
        __syncthreads();
        s[t] += a0;
        s[t + 512] += a1;
        __syncthreads();
    }
    if (t < NP) histS[t * NBKT_MAX + k] = s[t] - v0;                 // exclusive
    if (t + 512 < NP) histS[(t + 512) * NBKT_MAX + k] = s[t + 512] - v1;
    if (t == 0) rowtot[k] = s[1023];
}

// ---------------------------------------------------------------- scan bucket totals
__global__ __launch_bounds__(512) void k_scanbkt(const int* __restrict__ rowtot,
                                                 int* __restrict__ bktbase,
                                                 int* __restrict__ rs,
                                                 int nbkt, int n, int E) {
    __shared__ int s[512];
    const int t = threadIdx.x;
    int v = (t < nbkt) ? rowtot[t] : 0;
    s[t] = v;
    __syncthreads();
    for (int off = 1; off <= 256; off <<= 1) {
        int a = (t >= off) ? s[t - off] : 0;
        __syncthreads();
        s[t] += a;
        __syncthreads();
    }
    if (t < nbkt) bktbase[t] = s[t] - v;     // exclusive
    if (t == 0) { bktbase[nbkt] = E; rs[n] = E; }
}

// ---------------------------------------------------------------- FAT kernel: partition blocks ∥ gemm1 blocks
#define G1_ROWS 256
#define G1_KC 32
#define SMEM_BYTES 38912     // max(part 38912, gemm 36864+2048)

__device__ __forceinline__ void part_body(char* smem, int rid,
                                          const int* __restrict__ src,
                                          const int* __restrict__ dst,
                                          const int* __restrict__ histT,
                                          const int* __restrict__ histS,
                                          const int* __restrict__ bktbase,
                                          u32* __restrict__ pk,
                                          int E, int nbkt) {
    u32* sbuf = (u32*)smem;               // [PCH] 16KB
    u32* meta = sbuf + PCH;               // [PCH] 16KB
    int* lh   = (int*)(meta + PCH);       // [512] exclusive local base
    int* gb   = lh + 512;                 // [512] global base
    int* cur  = gb + 512;                 // [512] scan temp, then rank counter
    const int tid = threadIdx.x;
    const int base = rid * PCH;
    const int m = min(PCH, E - base);

    // local bucket bases from own histT row (no edge re-read)
    int c0 = (tid < nbkt) ? histT[rid * NBKT_MAX + tid] : 0;
    int c1 = (tid + 256 < nbkt) ? histT[rid * NBKT_MAX + tid + 256] : 0;
    cur[tid] = c0; cur[tid + 256] = c1;
    __syncthreads();
    for (int off = 1; off <= 256; off <<= 1) {
        int a0 = (tid >= off) ? cur[tid - off] : 0;
        int a1 = cur[tid + 256 - off];
        __syncthreads();
        cur[tid] += a0;
        cur[tid + 256] += a1;
        __syncthreads();
    }
    lh[tid] = cur[tid] - c0;
    lh[tid + 256] = cur[tid + 256] - c1;
    if (tid < nbkt) gb[tid] = bktbase[tid] + histS[rid * NBKT_MAX + tid];
    if (tid + 256 < nbkt) gb[tid + 256] = bktbase[tid + 256] + histS[rid * NBKT_MAX + tid + 256];
    __syncthreads();
    cur[tid] = 0; cur[tid + 256] = 0;
    __syncthreads();

    for (int i = tid; i < m; i += TPB) {
        int d = dst[base + i];
        int sv = src[base + i];
        int k = d >> 8;
        int r = atomicAdd(&cur[k], 1);
        int p = lh[k] + r;
        sbuf[p] = (u32)sv | ((u32)(d & 255) << 17);   // src 17b | dloc 8b
        meta[p] = ((u32)k << 12) | (u32)r;            // r < 4096
    }
    __syncthreads();
    for (int p = tid; p < m; p += TPB) {
        u32 mm = meta[p];
        pk[gb[mm >> 12] + (mm & 4095)] = sbuf[p];     // ascending runs per bucket
    }
}

__device__ __forceinline__ void gemm1_body(char* smem, int rid,
                                           const float* __restrict__ x,
                                           const float* __restrict__ W,
                                           const float* __restrict__ dinv,
                                           unsigned short* __restrict__ hsb, int n) {
    float (*xs)[36] = (float(*)[36])smem;             // [256][36] 36864B
    float* wl = (float*)(smem + 36864);               // [32*16] 2048B
    const int tid = threadIdx.x;
    const int row0 = rid * G1_ROWS;
    const int rg = tid >> 2;            // 0..63
    const int c0 = (tid & 3) * 4;       // 0,4,8,12

    float acc[4][4];
#pragma unroll
    for (int j = 0; j < 4; ++j)
#pragma unroll
        for (int c = 0; c < 4; ++c) acc[j][c] = 0.0f;

    for (int kc = 0; kc < 512; kc += G1_KC) {
        __syncthreads();
#pragma unroll
        for (int t = 0; t < 8; ++t) {
            int f4 = tid + TPB * t;
            int row = f4 >> 3;
            int kk = (f4 & 7) * 4;
            int grow = row0 + row;
            if (grow >= n) grow = n - 1;
            f32x4 v = __builtin_nontemporal_load(
                reinterpret_cast<const f32x4*>(&x[(size_t)grow * 512 + kc + kk]));
            *reinterpret_cast<f32x4*>(&xs[row][kk]) = v;
        }
        if (tid < 128) {
            int k = tid >> 2, cc = (tid & 3) * 4;
            *reinterpret_cast<float4*>(&wl[k * 16 + cc]) =
                *reinterpret_cast<const float4*>(&W[(size_t)(kc + k) * 16 + cc]);
        }
        __syncthreads();

#pragma unroll
        for (int k4 = 0; k4 < G1_KC; k4 += 4) {
            float w[4][4];
#pragma unroll
            for (int kk = 0; kk < 4; ++kk) {
                float4 wv = *reinterpret_cast<const float4*>(&wl[(k4 + kk) * 16 + c0]);
                w[kk][0] = wv.x; w[kk][1] = wv.y; w[kk][2] = wv.z; w[kk][3] = wv.w;
            }
#pragma unroll
            for (int j = 0; j < 4; ++j) {
                float4 xv = *reinterpret_cast<const float4*>(&xs[rg + 64 * j][k4]);
                float xk[4] = {xv.x, xv.y, xv.z, xv.w};
#pragma unroll
                for (int kk = 0; kk < 4; ++kk)
#pragma unroll
                    for (int c = 0; c < 4; ++c) acc[j][c] += xk[kk] * w[kk][c];
            }
        }
    }

#pragma unroll
    for (int j = 0; j < 4; ++j) {
        int grow = row0 + rg + 64 * j;
        if (grow < n) {
            float di = dinv[grow];
            ushort4 o;
            o.x = f2bf(acc[j][0] * di);
            o.y = f2bf(acc[j][1] * di);
            o.z = f2bf(acc[j][2] * di);
            o.w = f2bf(acc[j][3] * di);
            *reinterpret_cast<ushort4*>(&hsb[(size_t)grow * 16 + c0]) = o;
        }
    }
}

__global__ __launch_bounds__(TPB) void k_fat(const int* __restrict__ src,
                                             const int* __restrict__ dst,
                                             const int* __restrict__ histT,
                                             const int* __restrict__ histS,
                                             const int* __restrict__ bktbase,
                                             u32* __restrict__ pk,
                                             const float* __restrict__ x,
                                             const float* __restrict__ W1,
                                             const float* __restrict__ dinv,
                                             unsigned short* __restrict__ hsb,
                                             int E, int n, int nbkt,
                                             int NPART, int NGEMM) {
    __shared__ __align__(16) char smem[SMEM_BYTES];
    const int bid = blockIdx.x;
    bool isG = false;
    int rid;
    if (bid < 3 * NGEMM) {
        if (bid % 3 == 2) { isG = true; rid = bid / 3; }
        else rid = bid - (bid + 1) / 3;
    } else {
        rid = bid - NGEMM;
    }
    if (isG) {
        gemm1_body(smem, rid, x, W1, dinv, hsb, n);
    } else {
        if (rid < NPART)
            part_body(smem, rid, src, dst, histT, histS, bktbase, pk, E, nbkt);
    }
}

// ---------------------------------------------------------------- exact per-node sort within bucket
__global__ __launch_bounds__(TPB) void k_part2(const u32* __restrict__ pk,
                                               const int* __restrict__ bktbase,
                                               int* __restrict__ ssrc,
                                               int* __restrict__ rs,
                                               int n) {
    __shared__ u32 ebuf[MAXB];
    __shared__ int cnt[256], csum[256], s[256];
    const int t = threadIdx.x, b = blockIdx.x;
    const int r0 = bktbase[b], r1 = bktbase[b + 1];
    const int m = r1 - r0;
    cnt[t] = 0;
    __syncthreads();
    for (int i = t; i < m; i += TPB) {
        u32 v = pk[r0 + i];
        if (i < MAXB) ebuf[i] = v;
        atomicAdd(&cnt[(v >> 17) & 255], 1);
    }
    __syncthreads();
    int c = cnt[t];
    s[t] = c;
    __syncthreads();
    for (int off = 1; off <= 128; off <<= 1) {
        int a = (t >= off) ? s[t - off] : 0;
        __syncthreads();
        s[t] += a;
        __syncthreads();
    }
    int ex = s[t] - c;
    csum[t] = ex;
    int node = (b << 8) + t;
    if (node < n) rs[node] = r0 + ex;
    cnt[t] = 0;
    __syncthreads();
    for (int i = t; i < m; i += TPB) {
        u32 v = (i < MAXB) ? ebuf[i] : pk[r0 + i];
        int dl = (v >> 17) & 255;
        int r = atomicAdd(&cnt[dl], 1);
        ssrc[r0 + csum[dl] + r] = (int)(v & 0x1FFFF);
    }
}

// ---------------------------------------------------------------- layer-1 gather-agg, bf16 rows (32B), one pass.
__global__ __launch_bounds__(TPB) void k_gagg1(const int* __restrict__ rs,
                                               const int* __restrict__ ssrc,
                                               const unsigned short* __restrict__ hinB,
                                               const float* __restrict__ dinv,
                                               const float* __restrict__ b1,
                                               unsigned short* __restrict__ houtB, int n) {
    int node = blockIdx.x * 4 + (threadIdx.x >> 6);
    if (node >= n) return;
    const int lane = threadIdx.x & 63;
    const int j = lane >> 1;             // 0..31 edge sub-group
    const int hf = lane & 1;             // which 8-feature half (16B)
    const int r0 = rs[node], r1 = rs[node + 1];

    float a[8];
#pragma unroll
    for (int q = 0; q < 8; ++q) a[q] = 0.0f;

    for (int e = r0 + j; e < r1; e += 32) {
        int sv = ssrc[e];
        uint4 v = *reinterpret_cast<const uint4*>(&hinB[(size_t)sv * 16 + hf * 8]);
        a[0] += bflo(v.x); a[1] += bfhi(v.x);
        a[2] += bflo(v.y); a[3] += bfhi(v.y);
        a[4] += bflo(v.z); a[5] += bfhi(v.z);
        a[6] += bflo(v.w); a[7] += bfhi(v.w);
    }
#pragma unroll
    for (int m = 2; m <= 32; m <<= 1)
#pragma unroll
        for (int q = 0; q < 8; ++q) a[q] += __shfl_xor(a[q], m);

    if (j == 0) {
        float di = dinv[node];
        uint4 sv = *reinterpret_cast<const uint4*>(&hinB[(size_t)node * 16 + hf * 8]);
        float sf[8] = {bflo(sv.x), bfhi(sv.x), bflo(sv.y), bfhi(sv.y),
                       bflo(sv.z), bfhi(sv.z), bflo(sv.w), bfhi(sv.w)};
        unsigned short ob[8];
#pragma unroll
        for (int q = 0; q < 8; ++q) {
            float p = di * (a[q] + sf[q]);
            ob[q] = f2bf(di * fmaxf(p + b1[hf * 8 + q], 0.0f));
        }
        uint4 ov;
        ov.x = (u32)ob[0] | ((u32)ob[1] << 16);
        ov.y = (u32)ob[2] | ((u32)ob[3] << 16);
        ov.z = (u32)ob[4] | ((u32)ob[5] << 16);
        ov.w = (u32)ob[6] | ((u32)ob[7] << 16);
        *reinterpret_cast<uint4*>(&houtB[(size_t)node * 16 + hf * 8]) = ov;
    }
}

// ---------------------------------------------------------------- layer-2 gather-agg FUSED with GEMM2 (+bias)
__global__ __launch_bounds__(TPB) void k_gagg2f(const int* __restrict__ rs,
                                                const int* __restrict__ ssrc,
                                                const unsigned short* __restrict__ hinB,
                                                const float* __restrict__ dinv,
                                                const float* __restrict__ W2,
                                                const float* __restrict__ b2,
                                                float* __restrict__ out, int n) {
    __shared__ float pre_l[4][17];
    __shared__ float wl[16 * 40];
    __shared__ float bl[40];
    const int tid = threadIdx.x;
    for (int i = tid; i < 640; i += TPB) wl[i] = W2[i];
    if (tid < 40) bl[tid] = b2[tid];

    const int w = tid >> 6;              // node slot 0..3
    const int node = blockIdx.x * 4 + w;
    const int lane = tid & 63;
    const int j = lane >> 1;
    const int hf = lane & 1;

    if (node < n) {
        const int r0 = rs[node], r1 = rs[node + 1];
        float a[8];
#pragma unroll
        for (int q = 0; q < 8; ++q) a[q] = 0.0f;
        for (int e = r0 + j; e < r1; e += 32) {
            int sv = ssrc[e];
            uint4 v = *reinterpret_cast<const uint4*>(&hinB[(size_t)sv * 16 + hf * 8]);
            a[0] += bflo(v.x); a[1] += bfhi(v.x);
            a[2] += bflo(v.y); a[3] += bfhi(v.y);
            a[4] += bflo(v.z); a[5] += bfhi(v.z);
            a[6] += bflo(v.w); a[7] += bfhi(v.w);
        }
#pragma unroll
        for (int m = 2; m <= 32; m <<= 1)
#pragma unroll
            for (int q = 0; q < 8; ++q) a[q] += __shfl_xor(a[q], m);
        if (j == 0) {
            float di = dinv[node];
            uint4 sv = *reinterpret_cast<const uint4*>(&hinB[(size_t)node * 16 + hf * 8]);
            float sf[8] = {bflo(sv.x), bfhi(sv.x), bflo(sv.y), bfhi(sv.y),
                           bflo(sv.z), bfhi(sv.z), bflo(sv.w), bfhi(sv.w)};
#pragma unroll
            for (int q = 0; q < 8; ++q)
                pre_l[w][hf * 8 + q] = di * (a[q] + sf[q]);
        }
    }
    __syncthreads();

    if (tid < 160) {
        int ns = tid / 40, c = tid - ns * 40;
        int gnode = blockIdx.x * 4 + ns;
        if (gnode < n) {
            float acc = bl[c];
#pragma unroll
            for (int k = 0; k < 16; ++k) acc += pre_l[ns][k] * wl[k * 40 + c];
            out[(size_t)gnode * 40 + c] = acc;
        }
    }
}

extern "C" void kernel_launch(void* const* d_in, const int* in_sizes, int n_in,
                              void* d_out, int out_size, void* d_ws, size_t ws_size,
                              hipStream_t stream) {
    const float* x  = (const float*)d_in[0];
    const int*   ei = (const int*)d_in[1];
    const float* W1 = (const float*)d_in[2];
    const float* b1 = (const float*)d_in[3];
    const float* W2 = (const float*)d_in[4];
    const float* b2 = (const float*)d_in[5];
    float* out = (float*)d_out;

    const int n = in_sizes[0] / 512;
    const int E = in_sizes[1] / 2;
    const int* src = ei;
    const int* dst = ei + E;
    const int nbkt = (n + 255) >> 8;              // 391
    const int NPART = (E + PCH - 1) / PCH;        // 782
    const int NGEMM = (n + G1_ROWS - 1) / G1_ROWS;// 391

    // workspace layout
    char* w = (char*)d_ws;
    int*   histT   = (int*)w;     w += (size_t)NPART * NBKT_MAX * 4;
    int*   histS   = (int*)w;     w += (size_t)NPART * NBKT_MAX * 4;
    int*   rowtot  = (int*)w;     w += (size_t)NBKT_MAX * 4;
    int*   bktbase = (int*)w;     w += (size_t)(NBKT_MAX + 1) * 4;
    u32*   pk      = (u32*)w;     w += (size_t)E * 4;
    int*   ssrc    = (int*)w;     w += (size_t)E * 4;
    int*   rs      = (int*)w;     w += (size_t)(n + 1) * 4;
    int*   cnt     = (int*)w;     w += (size_t)n * 4;
    float* dinv    = (float*)w;   w += (size_t)n * 4;
    unsigned short* h1b = (unsigned short*)w;  w += (size_t)n * 16 * 2;
    unsigned short* h2b = (unsigned short*)w;  // n*16*2

    // fat grid: ensure all gemm blocks exist even if NPART < 2*NGEMM
    int fat_grid = NPART + NGEMM;
    if (fat_grid < 3 * NGEMM) fat_grid = 3 * NGEMM;

    hipMemsetAsync(cnt, 0, (size_t)n * 4, stream);
    k_cnthist<<<NPART, TPB, 0, stream>>>(dst, cnt, histT, E, nbkt);
    k_scanrow<<<nbkt, 512, 0, stream>>>(histT, histS, rowtot, cnt, dinv, NPART, n);
    k_scanbkt<<<1, 512, 0, stream>>>(rowtot, bktbase, rs, nbkt, n, E);
    k_fat    <<<fat_grid, TPB, 0, stream>>>(src, dst, histT, histS, bktbase, pk,
                                            x, W1, dinv, h1b, E, n, nbkt, NPART, NGEMM);
    k_part2  <<<nbkt, TPB, 0, stream>>>(pk, bktbase, ssrc, rs, n);
    k_gagg1  <<<(n + 3) / 4, TPB, 0, stream>>>(rs, ssrc, h1b, dinv, b1, h2b, n);
    k_gagg2f <<<(n + 3) / 4, TPB, 0, stream>>>(rs, ssrc, h2b, dinv, W2, b2, out, n);
}

// Round 11
// 233.211 us; speedup vs baseline: 1.5665x; 1.5665x over previous
//
#include <hip/hip_runtime.h>
#include <hip/hip_bf16.h>

// GCN 2-layer, counting-sort CSR + bf16-plane gather aggregation.
// N=100000, F_in=512, H=16, C=40, E=3200000.
//
// Algebra: with hs = dinv*h pre-scaled at the producer,
//   (A_hat h)[i] = dinv[i] * ( sum_{s in N(i)} hs[s] + hs[i] ).
// Layer2 aggregate-then-transform: A_hat(h2 W2) == (A_hat h2) W2.
//
// R11 = R9 serial structure + R10's lh-rebuild in k_part:
//   k_hist    (bucket histT, LDS histogram, one dst pass)
//   k_scanrow (histT column scan -> histS; histT kept raw for k_part)
//   k_scanbkt (bucket bases)
//   k_part    (LDS counting sort; local bases rebuilt from own histT row —
//              no edge re-read; coalesced pk writes)
//   k_part2   (exact per-node sort within bucket -> ssrc, rs, dinv; no
//              global atomics anywhere — R10 showed 3.2M random global
//              atomicAdds cost 135us with 100MB write amplification)
//   k_gemm1   (x nt-streamed; bf16 hs1 = dinv*(x@W1))
//   k_gagg1   (layer-1 gather, bf16 32B rows, L2-resident table)
//   k_gagg2f  (layer-2 gather fused with GEMM2 + bias)
// All global IO coalesced by construction (random 4B scatters amplify HBM
// writes 10-15x; measured R3/R5/R6/R10).

#define TPB 256
#define PCH 6144            // edges per hist/part chunk
#define NBKT_MAX 392        // buckets (100000>>8 = 391) padded
#define MAXB 10240          // max edges per bucket staged in LDS (avg 8184)

typedef unsigned int u32;
typedef float __attribute__((ext_vector_type(4))) f32x4;

__device__ __forceinline__ float bflo(u32 u) { return __uint_as_float(u << 16); }
__device__ __forceinline__ float bfhi(u32 u) { return __uint_as_float(u & 0xFFFF0000u); }
__device__ __forceinline__ unsigned short f2bf(float f) {
    __hip_bfloat16 h = __float2bfloat16(f);
    return *reinterpret_cast<unsigned short*>(&h);
}

// ---------------------------------------------------------------- bucket histogram
__global__ __launch_bounds__(TPB) void k_hist(const int* __restrict__ dst,
                                              int* __restrict__ histT,
                                              int E, int nbkt) {
    __shared__ int hist[NBKT_MAX];
    const int tid = threadIdx.x, blk = blockIdx.x;
    for (int k = tid; k < NBKT_MAX; k += TPB) hist[k] = 0;
    __syncthreads();
    const int base = blk * PCH;
    const int m = min(PCH, E - base);
    for (int i = tid; i < m; i += TPB) {
        int d = dst[base + i];
        atomicAdd(&hist[d >> 8], 1);
    }
    __syncthreads();
    for (int k = tid; k < nbkt; k += TPB) histT[blk * NBKT_MAX + k] = hist[k];
}

// ---------------------------------------------------------------- scan bucket rows across blocks (histT kept raw)
__global__ __launch_bounds__(512) void k_scanrow(const int* __restrict__ histT,
                                                 int* __restrict__ histS,
                                                 int* __restrict__ rowtot,
                                                 int NP) {
    __shared__ int s[1024];
    const int t = threadIdx.x, k = blockIdx.x;
    int v0 = (t < NP) ? histT[t * NBKT_MAX + k] : 0;
    int v1 = (t + 512 < NP) ? histT[(t + 512) * NBKT_MAX + k] : 0;
    s[t] = v0; s[t + 512] = v1;
    __syncthreads();
    for (int off = 1; off <= 512; off <<= 1) {
        int a0 = (t >= off) ? s[t - off] : 0;
        int a1 = s[t + 512 - off];
        __syncthreads();
        s[t] += a0;
        s[t + 512] += a1;
        __syncthreads();
    }
    if (t < NP) histS[t * NBKT_MAX + k] = s[t] - v0;                 // exclusive
    if (t + 512 < NP) histS[(t + 512) * NBKT_MAX + k] = s[t + 512] - v1;
    if (t == 0) rowtot[k] = s[1023];
}

// ---------------------------------------------------------------- scan bucket totals
__global__ __launch_bounds__(512) void k_scanbkt(const int* __restrict__ rowtot,
                                                 int* __restrict__ bktbase,
                                                 int* __restrict__ rs,
                                                 int nbkt, int n, int E) {
    __shared__ int s[512];
    const int t = threadIdx.x;
    int v = (t < nbkt) ? rowtot[t] : 0;
    s[t] = v;
    __syncthreads();
    for (int off = 1; off <= 256; off <<= 1) {
        int a = (t >= off) ? s[t - off] : 0;
        __syncthreads();
        s[t] += a;
        __syncthreads();
    }
    if (t < nbkt) bktbase[t] = s[t] - v;     // exclusive
    if (t == 0) { bktbase[nbkt] = E; rs[n] = E; }
}

// ---------------------------------------------------------------- partition into buckets (LDS sort, coalesced writes)
// Local bucket bases rebuilt from this block's histT row (saves the 6144-edge
// re-read + re-histogram of the R7-R9 version).
__global__ __launch_bounds__(TPB) void k_part(const int* __restrict__ src,
                                              const int* __restrict__ dst,
                                              const int* __restrict__ histT,
                                              const int* __restrict__ histS,
                                              const int* __restrict__ bktbase,
                                              u32* __restrict__ pk,
                                              int E, int nbkt) {
    __shared__ u32 sbuf[PCH];          // 24KB
    __shared__ u32 meta[PCH];          // 24KB
    __shared__ int lh[512], gb[512], cur[512];
    const int tid = threadIdx.x, blk = blockIdx.x;
    const int base = blk * PCH;
    const int m = min(PCH, E - base);

    // exclusive scan of own histT row -> local bases
    int c0 = (tid < nbkt) ? histT[blk * NBKT_MAX + tid] : 0;
    int c1 = (tid + 256 < nbkt) ? histT[blk * NBKT_MAX + tid + 256] : 0;
    cur[tid] = c0; cur[tid + 256] = c1;
    __syncthreads();
    for (int off = 1; off <= 256; off <<= 1) {
        int a0 = (tid >= off) ? cur[tid - off] : 0;
        int a1 = cur[tid + 256 - off];
        __syncthreads();
        cur[tid] += a0;
        cur[tid + 256] += a1;
        __syncthreads();
    }
    lh[tid] = cur[tid] - c0;
    lh[tid + 256] = cur[tid + 256] - c1;
    if (tid < nbkt) gb[tid] = bktbase[tid] + histS[blk * NBKT_MAX + tid];
    if (tid + 256 < nbkt) gb[tid + 256] = bktbase[tid + 256] + histS[blk * NBKT_MAX + tid + 256];
    __syncthreads();
    cur[tid] = 0; cur[tid + 256] = 0;
    __syncthreads();

    for (int i = tid; i < m; i += TPB) {
        int d = dst[base + i];
        int sv = src[base + i];
        int k = d >> 8;
        int r = atomicAdd(&cur[k], 1);
        int p = lh[k] + r;
        sbuf[p] = (u32)sv | ((u32)(d & 255) << 17);   // src 17b | dloc 8b
        meta[p] = ((u32)k << 13) | (u32)r;            // r < 6144 (13b)
    }
    __syncthreads();
    for (int p = tid; p < m; p += TPB) {
        u32 mm = meta[p];
        pk[gb[mm >> 13] + (mm & 8191)] = sbuf[p];     // ascending runs per bucket
    }
}

// ---------------------------------------------------------------- exact per-node sort within bucket (+ dinv)
__global__ __launch_bounds__(TPB) void k_part2(const u32* __restrict__ pk,
                                               const int* __restrict__ bktbase,
                                               int* __restrict__ ssrc,
                                               int* __restrict__ rs,
                                               float* __restrict__ dinv,
                                               int n) {
    __shared__ u32 ebuf[MAXB];
    __shared__ int cnt[256], csum[256], s[256];
    const int t = threadIdx.x, b = blockIdx.x;
    const int r0 = bktbase[b], r1 = bktbase[b + 1];
    const int m = r1 - r0;
    cnt[t] = 0;
    __syncthreads();
    for (int i = t; i < m; i += TPB) {
        u32 v = pk[r0 + i];
        if (i < MAXB) ebuf[i] = v;
        atomicAdd(&cnt[(v >> 17) & 255], 1);
    }
    __syncthreads();
    int c = cnt[t];
    s[t] = c;
    __syncthreads();
    for (int off = 1; off <= 128; off <<= 1) {
        int a = (t >= off) ? s[t - off] : 0;
        __syncthreads();
        s[t] += a;
        __syncthreads();
    }
    int ex = s[t] - c;
    csum[t] = ex;
    int node = (b << 8) + t;
    if (node < n) {
        rs[node] = r0 + ex;
        dinv[node] = rsqrtf((float)(c + 1));   // +1 self loop; no global atomics
    }
    cnt[t] = 0;
    __syncthreads();
    for (int i = t; i < m; i += TPB) {
        u32 v = (i < MAXB) ? ebuf[i] : pk[r0 + i];
        int dl = (v >> 17) & 255;
        int r = atomicAdd(&cnt[dl], 1);
        ssrc[r0 + csum[dl] + r] = (int)(v & 0x1FFFF);
    }
}

// ---------------------------------------------------------------- GEMM1: hs1b[n,16](bf16) = dinv * (x @ W1)
#define G1_ROWS 256
#define G1_KC 32
__global__ __launch_bounds__(TPB) void k_gemm1(const float* __restrict__ x,
                                               const float* __restrict__ W,
                                               const float* __restrict__ dinv,
                                               unsigned short* __restrict__ hsb, int n) {
    __shared__ float xs[G1_ROWS][36];
    __shared__ float wl[G1_KC][16];
    const int tid = threadIdx.x;
    const int row0 = blockIdx.x * G1_ROWS;
    const int rg = tid >> 2;            // 0..63
    const int c0 = (tid & 3) * 4;       // 0,4,8,12

    float acc[4][4];
#pragma unroll
    for (int j = 0; j < 4; ++j)
#pragma unroll
        for (int c = 0; c < 4; ++c) acc[j][c] = 0.0f;

    for (int kc = 0; kc < 512; kc += G1_KC) {
        __syncthreads();
#pragma unroll
        for (int t = 0; t < 8; ++t) {
            int f4 = tid + TPB * t;
            int row = f4 >> 3;
            int kk = (f4 & 7) * 4;
            int grow = row0 + row;
            if (grow >= n) grow = n - 1;
            f32x4 v = __builtin_nontemporal_load(
                reinterpret_cast<const f32x4*>(&x[(size_t)grow * 512 + kc + kk]));
            *reinterpret_cast<f32x4*>(&xs[row][kk]) = v;
        }
        if (tid < 128) {
            int k = tid >> 2, cc = (tid & 3) * 4;
            *reinterpret_cast<float4*>(&wl[k][cc]) =
                *reinterpret_cast<const float4*>(&W[(size_t)(kc + k) * 16 + cc]);
        }
        __syncthreads();

#pragma unroll
        for (int k4 = 0; k4 < G1_KC; k4 += 4) {
            float w[4][4];
#pragma unroll
            for (int kk = 0; kk < 4; ++kk) {
                float4 wv = *reinterpret_cast<const float4*>(&wl[k4 + kk][c0]);
                w[kk][0] = wv.x; w[kk][1] = wv.y; w[kk][2] = wv.z; w[kk][3] = wv.w;
            }
#pragma unroll
            for (int j = 0; j < 4; ++j) {
                float4 xv = *reinterpret_cast<const float4*>(&xs[rg + 64 * j][k4]);
                float xk[4] = {xv.x, xv.y, xv.z, xv.w};
#pragma unroll
                for (int kk = 0; kk < 4; ++kk)
#pragma unroll
                    for (int c = 0; c < 4; ++c) acc[j][c] += xk[kk] * w[kk][c];
            }
        }
    }

#pragma unroll
    for (int j = 0; j < 4; ++j) {
        int grow = row0 + rg + 64 * j;
        if (grow < n) {
            float di = dinv[grow];
            ushort4 o;
            o.x = f2bf(acc[j][0] * di);
            o.y = f2bf(acc[j][1] * di);
            o.z = f2bf(acc[j][2] * di);
            o.w = f2bf(acc[j][3] * di);
            *reinterpret_cast<ushort4*>(&hsb[(size_t)grow * 16 + c0]) = o;
        }
    }
}

// ---------------------------------------------------------------- layer-1 gather-agg, bf16 rows (32B), one pass.
__global__ __launch_bounds__(TPB) void k_gagg1(const int* __restrict__ rs,
                                               const int* __restrict__ ssrc,
                                               const unsigned short* __restrict__ hinB,
                                               const float* __restrict__ dinv,
                                               const float* __restrict__ b1,
                                               unsigned short* __restrict__ houtB, int n) {
    int node = blockIdx.x * 4 + (threadIdx.x >> 6);
    if (node >= n) return;
    const int lane = threadIdx.x & 63;
    const int j = lane >> 1;             // 0..31 edge sub-group
    const int hf = lane & 1;             // which 8-feature half (16B)
    const int r0 = rs[node], r1 = rs[node + 1];

    float a[8];
#pragma unroll
    for (int q = 0; q < 8; ++q) a[q] = 0.0f;

    for (int e = r0 + j; e < r1; e += 32) {
        int sv = ssrc[e];
        uint4 v = *reinterpret_cast<const uint4*>(&hinB[(size_t)sv * 16 + hf * 8]);
        a[0] += bflo(v.x); a[1] += bfhi(v.x);
        a[2] += bflo(v.y); a[3] += bfhi(v.y);
        a[4] += bflo(v.z); a[5] += bfhi(v.z);
        a[6] += bflo(v.w); a[7] += bfhi(v.w);
    }
#pragma unroll
    for (int m = 2; m <= 32; m <<= 1)
#pragma unroll
        for (int q = 0; q < 8; ++q) a[q] += __shfl_xor(a[q], m);

    if (j == 0) {
        float di = dinv[node];
        uint4 sv = *reinterpret_cast<const uint4*>(&hinB[(size_t)node * 16 + hf * 8]);
        float sf[8] = {bflo(sv.x), bfhi(sv.x), bflo(sv.y), bfhi(sv.y),
                       bflo(sv.z), bfhi(sv.z), bflo(sv.w), bfhi(sv.w)};
        unsigned short ob[8];
#pragma unroll
        for (int q = 0; q < 8; ++q) {
            float p = di * (a[q] + sf[q]);
            ob[q] = f2bf(di * fmaxf(p + b1[hf * 8 + q], 0.0f));
        }
        uint4 ov;
        ov.x = (u32)ob[0] | ((u32)ob[1] << 16);
        ov.y = (u32)ob[2] | ((u32)ob[3] << 16);
        ov.z = (u32)ob[4] | ((u32)ob[5] << 16);
        ov.w = (u32)ob[6] | ((u32)ob[7] << 16);
        *reinterpret_cast<uint4*>(&houtB[(size_t)node * 16 + hf * 8]) = ov;
    }
}

// ---------------------------------------------------------------- layer-2 gather-agg FUSED with GEMM2 (+bias)
__global__ __launch_bounds__(TPB) void k_gagg2f(const int* __restrict__ rs,
                                                const int* __restrict__ ssrc,
                                                const unsigned short* __restrict__ hinB,
                                                const float* __restrict__ dinv,
                                                const float* __restrict__ W2,
                                                const float* __restrict__ b2,
                                                float* __restrict__ out, int n) {
    __shared__ float pre_l[4][17];
    __shared__ float wl[16 * 40];
    __shared__ float bl[40];
    const int tid = threadIdx.x;
    for (int i = tid; i < 640; i += TPB) wl[i] = W2[i];
    if (tid < 40) bl[tid] = b2[tid];

    const int w = tid >> 6;              // node slot 0..3
    const int node = blockIdx.x * 4 + w;
    const int lane = tid & 63;
    const int j = lane >> 1;
    const int hf = lane & 1;

    if (node < n) {
        const int r0 = rs[node], r1 = rs[node + 1];
        float a[8];
#pragma unroll
        for (int q = 0; q < 8; ++q) a[q] = 0.0f;
        for (int e = r0 + j; e < r1; e += 32) {
            int sv = ssrc[e];
            uint4 v = *reinterpret_cast<const uint4*>(&hinB[(size_t)sv * 16 + hf * 8]);
            a[0] += bflo(v.x); a[1] += bfhi(v.x);
            a[2] += bflo(v.y); a[3] += bfhi(v.y);
            a[4] += bflo(v.z); a[5] += bfhi(v.z);
            a[6] += bflo(v.w); a[7] += bfhi(v.w);
        }
#pragma unroll
        for (int m = 2; m <= 32; m <<= 1)
#pragma unroll
            for (int q = 0; q < 8; ++q) a[q] += __shfl_xor(a[q], m);
        if (j == 0) {
            float di = dinv[node];
            uint4 sv = *reinterpret_cast<const uint4*>(&hinB[(size_t)node * 16 + hf * 8]);
            float sf[8] = {bflo(sv.x), bfhi(sv.x), bflo(sv.y), bfhi(sv.y),
                           bflo(sv.z), bfhi(sv.z), bflo(sv.w), bfhi(sv.w)};
#pragma unroll
            for (int q = 0; q < 8; ++q)
                pre_l[w][hf * 8 + q] = di * (a[q] + sf[q]);
        }
    }
    __syncthreads();

    if (tid < 160) {
        int ns = tid / 40, c = tid - ns * 40;
        int gnode = blockIdx.x * 4 + ns;
        if (gnode < n) {
            float acc = bl[c];
#pragma unroll
            for (int k = 0; k < 16; ++k) acc += pre_l[ns][k] * wl[k * 40 + c];
            out[(size_t)gnode * 40 + c] = acc;
        }
    }
}

extern "C" void kernel_launch(void* const* d_in, const int* in_sizes, int n_in,
                              void* d_out, int out_size, void* d_ws, size_t ws_size,
                              hipStream_t stream) {
    const float* x  = (const float*)d_in[0];
    const int*   ei = (const int*)d_in[1];
    const float* W1 = (const float*)d_in[2];
    const float* b1 = (const float*)d_in[3];
    const float* W2 = (const float*)d_in[4];
    const float* b2 = (const float*)d_in[5];
    float* out = (float*)d_out;

    const int n = in_sizes[0] / 512;
    const int E = in_sizes[1] / 2;
    const int* src = ei;
    const int* dst = ei + E;
    const int nbkt = (n + 255) >> 8;              // 391
    const int NP = (E + PCH - 1) / PCH;           // 521

    // workspace layout
    char* w = (char*)d_ws;
    int*   histT   = (int*)w;     w += (size_t)NP * NBKT_MAX * 4;
    int*   histS   = (int*)w;     w += (size_t)NP * NBKT_MAX * 4;
    int*   rowtot  = (int*)w;     w += (size_t)NBKT_MAX * 4;
    int*   bktbase = (int*)w;     w += (size_t)(NBKT_MAX + 1) * 4;
    u32*   pk      = (u32*)w;     w += (size_t)E * 4;
    int*   ssrc    = (int*)w;     w += (size_t)E * 4;
    int*   rs      = (int*)w;     w += (size_t)(n + 1) * 4;
    float* dinv    = (float*)w;   w += (size_t)n * 4;
    unsigned short* h1b = (unsigned short*)w;  w += (size_t)n * 16 * 2;
    unsigned short* h2b = (unsigned short*)w;  // n*16*2

    k_hist   <<<NP, TPB, 0, stream>>>(dst, histT, E, nbkt);
    k_scanrow<<<nbkt, 512, 0, stream>>>(histT, histS, rowtot, NP);
    k_scanbkt<<<1, 512, 0, stream>>>(rowtot, bktbase, rs, nbkt, n, E);
    k_part   <<<NP, TPB, 0, stream>>>(src, dst, histT, histS, bktbase, pk, E, nbkt);
    k_part2  <<<nbkt, TPB, 0, stream>>>(pk, bktbase, ssrc, rs, dinv, n);
    k_gemm1  <<<(n + G1_ROWS - 1) / G1_ROWS, TPB, 0, stream>>>(x, W1, dinv, h1b, n);
    k_gagg1  <<<(n + 3) / 4, TPB, 0, stream>>>(rs, ssrc, h1b, dinv, b1, h2b, n);
    k_gagg2f <<<(n + 3) / 4, TPB, 0, stream>>>(rs, ssrc, h2b, dinv, W2, b2, out, n);
}

// Round 12
// 231.364 us; speedup vs baseline: 1.5790x; 1.0080x over previous
//
#include <hip/hip_runtime.h>
#include <hip/hip_bf16.h>

// GCN 2-layer, counting-sort CSR + bf16-plane gather aggregation.
// N=100000, F_in=512, H=16, C=40, E=3200000.
//
// Algebra: with hs = dinv*h pre-scaled at the producer,
//   (A_hat h)[i] = dinv[i] * ( sum_{s in N(i)} hs[s] + hs[i] ).
// Layer2 aggregate-then-transform: A_hat(h2 W2) == (A_hat h2) W2.
//
// R12 = R11 + (a) wave-privatized LDS histogram in k_hist (4x less atomic
// contention), (b) register-prefetch software pipeline in k_gemm1 (next
// K-chunk's loads issued before compute, consumed after the barrier).
// All global IO coalesced by construction (random 4B scatters amplify HBM
// writes 10-15x; measured R3/R5/R6/R10). No global atomics anywhere.

#define TPB 256
#define PCH 6144            // edges per hist/part chunk
#define NBKT_MAX 392        // buckets (100000>>8 = 391) padded
#define MAXB 10240          // max edges per bucket staged in LDS (avg 8184)

typedef unsigned int u32;
typedef float __attribute__((ext_vector_type(4))) f32x4;

__device__ __forceinline__ float bflo(u32 u) { return __uint_as_float(u << 16); }
__device__ __forceinline__ float bfhi(u32 u) { return __uint_as_float(u & 0xFFFF0000u); }
__device__ __forceinline__ unsigned short f2bf(float f) {
    __hip_bfloat16 h = __float2bfloat16(f);
    return *reinterpret_cast<unsigned short*>(&h);
}

// ---------------------------------------------------------------- bucket histogram (wave-privatized)
__global__ __launch_bounds__(TPB) void k_hist(const int* __restrict__ dst,
                                              int* __restrict__ histT,
                                              int E, int nbkt) {
    __shared__ int hist[4][NBKT_MAX];
    const int tid = threadIdx.x, blk = blockIdx.x;
    const int wv = tid >> 6;
    for (int k = tid; k < 4 * NBKT_MAX; k += TPB) (&hist[0][0])[k] = 0;
    __syncthreads();
    const int base = blk * PCH;
    const int m = min(PCH, E - base);
    for (int i = tid; i < m; i += TPB) {
        int d = dst[base + i];
        atomicAdd(&hist[wv][d >> 8], 1);
    }
    __syncthreads();
    for (int k = tid; k < nbkt; k += TPB)
        histT[blk * NBKT_MAX + k] = hist[0][k] + hist[1][k] + hist[2][k] + hist[3][k];
}

// ---------------------------------------------------------------- scan bucket rows across blocks (histT kept raw)
__global__ __launch_bounds__(512) void k_scanrow(const int* __restrict__ histT,
                                                 int* __restrict__ histS,
                                                 int* __restrict__ rowtot,
                                                 int NP) {
    __shared__ int s[1024];
    const int t = threadIdx.x, k = blockIdx.x;
    int v0 = (t < NP) ? histT[t * NBKT_MAX + k] : 0;
    int v1 = (t + 512 < NP) ? histT[(t + 512) * NBKT_MAX + k] : 0;
    s[t] = v0; s[t + 512] = v1;
    __syncthreads();
    for (int off = 1; off <= 512; off <<= 1) {
        int a0 = (t >= off) ? s[t - off] : 0;
        int a1 = s[t + 512 - off];
        __syncthreads();
        s[t] += a0;
        s[t + 512] += a1;
        __syncthreads();
    }
    if (t < NP) histS[t * NBKT_MAX + k] = s[t] - v0;                 // exclusive
    if (t + 512 < NP) histS[(t + 512) * NBKT_MAX + k] = s[t + 512] - v1;
    if (t == 0) rowtot[k] = s[1023];
}

// ---------------------------------------------------------------- scan bucket totals
__global__ __launch_bounds__(512) void k_scanbkt(const int* __restrict__ rowtot,
                                                 int* __restrict__ bktbase,
                                                 int* __restrict__ rs,
                                                 int nbkt, int n, int E) {
    __shared__ int s[512];
    const int t = threadIdx.x;
    int v = (t < nbkt) ? rowtot[t] : 0;
    s[t] = v;
    __syncthreads();
    for (int off = 1; off <= 256; off <<= 1) {
        int a = (t >= off) ? s[t - off] : 0;
        __syncthreads();
        s[t] += a;
        __syncthreads();
    }
    if (t < nbkt) bktbase[t] = s[t] - v;     // exclusive
    if (t == 0) { bktbase[nbkt] = E; rs[n] = E; }
}

// ---------------------------------------------------------------- partition into buckets (LDS sort, coalesced writes)
__global__ __launch_bounds__(TPB) void k_part(const int* __restrict__ src,
                                              const int* __restrict__ dst,
                                              const int* __restrict__ histT,
                                              const int* __restrict__ histS,
                                              const int* __restrict__ bktbase,
                                              u32* __restrict__ pk,
                                              int E, int nbkt) {
    __shared__ u32 sbuf[PCH];          // 24KB
    __shared__ u32 meta[PCH];          // 24KB
    __shared__ int lh[512], gb[512], cur[512];
    const int tid = threadIdx.x, blk = blockIdx.x;
    const int base = blk * PCH;
    const int m = min(PCH, E - base);

    // exclusive scan of own histT row -> local bases
    int c0 = (tid < nbkt) ? histT[blk * NBKT_MAX + tid] : 0;
    int c1 = (tid + 256 < nbkt) ? histT[blk * NBKT_MAX + tid + 256] : 0;
    cur[tid] = c0; cur[tid + 256] = c1;
    __syncthreads();
    for (int off = 1; off <= 256; off <<= 1) {
        int a0 = (tid >= off) ? cur[tid - off] : 0;
        int a1 = cur[tid + 256 - off];
        __syncthreads();
        cur[tid] += a0;
        cur[tid + 256] += a1;
        __syncthreads();
    }
    lh[tid] = cur[tid] - c0;
    lh[tid + 256] = cur[tid + 256] - c1;
    if (tid < nbkt) gb[tid] = bktbase[tid] + histS[blk * NBKT_MAX + tid];
    if (tid + 256 < nbkt) gb[tid + 256] = bktbase[tid + 256] + histS[blk * NBKT_MAX + tid + 256];
    __syncthreads();
    cur[tid] = 0; cur[tid + 256] = 0;
    __syncthreads();

    for (int i = tid; i < m; i += TPB) {
        int d = dst[base + i];
        int sv = src[base + i];
        int k = d >> 8;
        int r = atomicAdd(&cur[k], 1);
        int p = lh[k] + r;
        sbuf[p] = (u32)sv | ((u32)(d & 255) << 17);   // src 17b | dloc 8b
        meta[p] = ((u32)k << 13) | (u32)r;            // r < 6144 (13b)
    }
    __syncthreads();
    for (int p = tid; p < m; p += TPB) {
        u32 mm = meta[p];
        pk[gb[mm >> 13] + (mm & 8191)] = sbuf[p];     // ascending runs per bucket
    }
}

// ---------------------------------------------------------------- exact per-node sort within bucket (+ dinv)
__global__ __launch_bounds__(TPB) void k_part2(const u32* __restrict__ pk,
                                               const int* __restrict__ bktbase,
                                               int* __restrict__ ssrc,
                                               int* __restrict__ rs,
                                               float* __restrict__ dinv,
                                               int n) {
    __shared__ u32 ebuf[MAXB];
    __shared__ int cnt[256], csum[256], s[256];
    const int t = threadIdx.x, b = blockIdx.x;
    const int r0 = bktbase[b], r1 = bktbase[b + 1];
    const int m = r1 - r0;
    cnt[t] = 0;
    __syncthreads();
    for (int i = t; i < m; i += TPB) {
        u32 v = pk[r0 + i];
        if (i < MAXB) ebuf[i] = v;
        atomicAdd(&cnt[(v >> 17) & 255], 1);
    }
    __syncthreads();
    int c = cnt[t];
    s[t] = c;
    __syncthreads();
    for (int off = 1; off <= 128; off <<= 1) {
        int a = (t >= off) ? s[t - off] : 0;
        __syncthreads();
        s[t] += a;
        __syncthreads();
    }
    int ex = s[t] - c;
    csum[t] = ex;
    int node = (b << 8) + t;
    if (node < n) {
        rs[node] = r0 + ex;
        dinv[node] = rsqrtf((float)(c + 1));   // +1 self loop; no global atomics
    }
    cnt[t] = 0;
    __syncthreads();
    for (int i = t; i < m; i += TPB) {
        u32 v = (i < MAXB) ? ebuf[i] : pk[r0 + i];
        int dl = (v >> 17) & 255;
        int r = atomicAdd(&cnt[dl], 1);
        ssrc[r0 + csum[dl] + r] = (int)(v & 0x1FFFF);
    }
}

// ---------------------------------------------------------------- GEMM1: hs1b[n,16](bf16) = dinv * (x @ W1)
// Register-prefetch pipeline: next K-chunk's 8 float4 issued right after the
// LDS write, consumed after the next barrier (HBM latency under FMA work).
#define G1_ROWS 256
#define G1_KC 32
__global__ __launch_bounds__(TPB) void k_gemm1(const float* __restrict__ x,
                                               const float* __restrict__ W,
                                               const float* __restrict__ dinv,
                                               unsigned short* __restrict__ hsb, int n) {
    __shared__ float xs[G1_ROWS][36];
    __shared__ float wl[G1_KC][16];
    const int tid = threadIdx.x;
    const int row0 = blockIdx.x * G1_ROWS;
    const int rg = tid >> 2;            // 0..63
    const int c0 = (tid & 3) * 4;       // 0,4,8,12

    // per-thread staging addresses (row, kk fixed across chunks)
    int myrow[8], mykk[8];
    const float* mybase[8];
#pragma unroll
    for (int t = 0; t < 8; ++t) {
        int f4 = tid + TPB * t;
        myrow[t] = f4 >> 3;
        mykk[t] = (f4 & 7) * 4;
        int grow = row0 + myrow[t];
        if (grow >= n) grow = n - 1;
        mybase[t] = &x[(size_t)grow * 512 + mykk[t]];
    }

    float acc[4][4];
#pragma unroll
    for (int j = 0; j < 4; ++j)
#pragma unroll
        for (int c = 0; c < 4; ++c) acc[j][c] = 0.0f;

    f32x4 pf[8];
#pragma unroll
    for (int t = 0; t < 8; ++t)
        pf[t] = __builtin_nontemporal_load(reinterpret_cast<const f32x4*>(mybase[t]));

    for (int kc = 0; kc < 512; kc += G1_KC) {
        __syncthreads();
#pragma unroll
        for (int t = 0; t < 8; ++t)
            *reinterpret_cast<f32x4*>(&xs[myrow[t]][mykk[t]]) = pf[t];
        if (tid < 128) {
            int k = tid >> 2, cc = (tid & 3) * 4;
            *reinterpret_cast<float4*>(&wl[k][cc]) =
                *reinterpret_cast<const float4*>(&W[(size_t)(kc + k) * 16 + cc]);
        }
        __syncthreads();

        if (kc + G1_KC < 512) {
#pragma unroll
            for (int t = 0; t < 8; ++t)
                pf[t] = __builtin_nontemporal_load(
                    reinterpret_cast<const f32x4*>(mybase[t] + kc + G1_KC));
        }

#pragma unroll
        for (int k4 = 0; k4 < G1_KC; k4 += 4) {
            float w[4][4];
#pragma unroll
            for (int kk = 0; kk < 4; ++kk) {
                float4 wv = *reinterpret_cast<const float4*>(&wl[k4 + kk][c0]);
                w[kk][0] = wv.x; w[kk][1] = wv.y; w[kk][2] = wv.z; w[kk][3] = wv.w;
            }
#pragma unroll
            for (int j = 0; j < 4; ++j) {
                float4 xv = *reinterpret_cast<const float4*>(&xs[rg + 64 * j][k4]);
                float xk[4] = {xv.x, xv.y, xv.z, xv.w};
#pragma unroll
                for (int kk = 0; kk < 4; ++kk)
#pragma unroll
                    for (int c = 0; c < 4; ++c) acc[j][c] += xk[kk] * w[kk][c];
            }
        }
    }

#pragma unroll
    for (int j = 0; j < 4; ++j) {
        int grow = row0 + rg + 64 * j;
        if (grow < n) {
            float di = dinv[grow];
            ushort4 o;
            o.x = f2bf(acc[j][0] * di);
            o.y = f2bf(acc[j][1] * di);
            o.z = f2bf(acc[j][2] * di);
            o.w = f2bf(acc[j][3] * di);
            *reinterpret_cast<ushort4*>(&hsb[(size_t)grow * 16 + c0]) = o;
        }
    }
}

// ---------------------------------------------------------------- layer-1 gather-agg, bf16 rows (32B), one pass.
__global__ __launch_bounds__(TPB) void k_gagg1(const int* __restrict__ rs,
                                               const int* __restrict__ ssrc,
                                               const unsigned short* __restrict__ hinB,
                                               const float* __restrict__ dinv,
                                               const float* __restrict__ b1,
                                               unsigned short* __restrict__ houtB, int n) {
    int node = blockIdx.x * 4 + (threadIdx.x >> 6);
    if (node >= n) return;
    const int lane = threadIdx.x & 63;
    const int j = lane >> 1;             // 0..31 edge sub-group
    const int hf = lane & 1;             // which 8-feature half (16B)
    const int r0 = rs[node], r1 = rs[node + 1];

    float a[8];
#pragma unroll
    for (int q = 0; q < 8; ++q) a[q] = 0.0f;

    for (int e = r0 + j; e < r1; e += 32) {
        int sv = ssrc[e];
        uint4 v = *reinterpret_cast<const uint4*>(&hinB[(size_t)sv * 16 + hf * 8]);
        a[0] += bflo(v.x); a[1] += bfhi(v.x);
        a[2] += bflo(v.y); a[3] += bfhi(v.y);
        a[4] += bflo(v.z); a[5] += bfhi(v.z);
        a[6] += bflo(v.w); a[7] += bfhi(v.w);
    }
#pragma unroll
    for (int m = 2; m <= 32; m <<= 1)
#pragma unroll
        for (int q = 0; q < 8; ++q) a[q] += __shfl_xor(a[q], m);

    if (j == 0) {
        float di = dinv[node];
        uint4 sv = *reinterpret_cast<const uint4*>(&hinB[(size_t)node * 16 + hf * 8]);
        float sf[8] = {bflo(sv.x), bfhi(sv.x), bflo(sv.y), bfhi(sv.y),
                       bflo(sv.z), bfhi(sv.z), bflo(sv.w), bfhi(sv.w)};
        unsigned short ob[8];
#pragma unroll
        for (int q = 0; q < 8; ++q) {
            float p = di * (a[q] + sf[q]);
            ob[q] = f2bf(di * fmaxf(p + b1[hf * 8 + q], 0.0f));
        }
        uint4 ov;
        ov.x = (u32)ob[0] | ((u32)ob[1] << 16);
        ov.y = (u32)ob[2] | ((u32)ob[3] << 16);
        ov.z = (u32)ob[4] | ((u32)ob[5] << 16);
        ov.w = (u32)ob[6] | ((u32)ob[7] << 16);
        *reinterpret_cast<uint4*>(&houtB[(size_t)node * 16 + hf * 8]) = ov;
    }
}

// ---------------------------------------------------------------- layer-2 gather-agg FUSED with GEMM2 (+bias)
__global__ __launch_bounds__(TPB) void k_gagg2f(const int* __restrict__ rs,
                                                const int* __restrict__ ssrc,
                                                const unsigned short* __restrict__ hinB,
                                                const float* __restrict__ dinv,
                                                const float* __restrict__ W2,
                                                const float* __restrict__ b2,
                                                float* __restrict__ out, int n) {
    __shared__ float pre_l[4][17];
    __shared__ float wl[16 * 40];
    __shared__ float bl[40];
    const int tid = threadIdx.x;
    for (int i = tid; i < 640; i += TPB) wl[i] = W2[i];
    if (tid < 40) bl[tid] = b2[tid];

    const int w = tid >> 6;              // node slot 0..3
    const int node = blockIdx.x * 4 + w;
    const int lane = tid & 63;
    const int j = lane >> 1;
    const int hf = lane & 1;

    if (node < n) {
        const int r0 = rs[node], r1 = rs[node + 1];
        float a[8];
#pragma unroll
        for (int q = 0; q < 8; ++q) a[q] = 0.0f;
        for (int e = r0 + j; e < r1; e += 32) {
            int sv = ssrc[e];
            uint4 v = *reinterpret_cast<const uint4*>(&hinB[(size_t)sv * 16 + hf * 8]);
            a[0] += bflo(v.x); a[1] += bfhi(v.x);
            a[2] += bflo(v.y); a[3] += bfhi(v.y);
            a[4] += bflo(v.z); a[5] += bfhi(v.z);
            a[6] += bflo(v.w); a[7] += bfhi(v.w);
        }
#pragma unroll
        for (int m = 2; m <= 32; m <<= 1)
#pragma unroll
            for (int q = 0; q < 8; ++q) a[q] += __shfl_xor(a[q], m);
        if (j == 0) {
            float di = dinv[node];
            uint4 sv = *reinterpret_cast<const uint4*>(&hinB[(size_t)node * 16 + hf * 8]);
            float sf[8] = {bflo(sv.x), bfhi(sv.x), bflo(sv.y), bfhi(sv.y),
                           bflo(sv.z), bfhi(sv.z), bflo(sv.w), bfhi(sv.w)};
#pragma unroll
            for (int q = 0; q < 8; ++q)
                pre_l[w][hf * 8 + q] = di * (a[q] + sf[q]);
        }
    }
    __syncthreads();

    if (tid < 160) {
        int ns = tid / 40, c = tid - ns * 40;
        int gnode = blockIdx.x * 4 + ns;
        if (gnode < n) {
            float acc = bl[c];
#pragma unroll
            for (int k = 0; k < 16; ++k) acc += pre_l[ns][k] * wl[k * 40 + c];
            out[(size_t)gnode * 40 + c] = acc;
        }
    }
}

extern "C" void kernel_launch(void* const* d_in, const int* in_sizes, int n_in,
                              void* d_out, int out_size, void* d_ws, size_t ws_size,
                              hipStream_t stream) {
    const float* x  = (const float*)d_in[0];
    const int*   ei = (const int*)d_in[1];
    const float* W1 = (const float*)d_in[2];
    const float* b1 = (const float*)d_in[3];
    const float* W2 = (const float*)d_in[4];
    const float* b2 = (const float*)d_in[5];
    float* out = (float*)d_out;

    const int n = in_sizes[0] / 512;
    const int E = in_sizes[1] / 2;
    const int* src = ei;
    const int* dst = ei + E;
    const int nbkt = (n + 255) >> 8;              // 391
    const int NP = (E + PCH - 1) / PCH;           // 521

    // workspace layout
    char* w = (char*)d_ws;
    int*   histT   = (int*)w;     w += (size_t)NP * NBKT_MAX * 4;
    int*   histS   = (int*)w;     w += (size_t)NP * NBKT_MAX * 4;
    int*   rowtot  = (int*)w;     w += (size_t)NBKT_MAX * 4;
    int*   bktbase = (int*)w;     w += (size_t)(NBKT_MAX + 1) * 4;
    u32*   pk      = (u32*)w;     w += (size_t)E * 4;
    int*   ssrc    = (int*)w;     w += (size_t)E * 4;
    int*   rs      = (int*)w;     w += (size_t)(n + 1) * 4;
    float* dinv    = (float*)w;   w += (size_t)n * 4;
    unsigned short* h1b = (unsigned short*)w;  w += (size_t)n * 16 * 2;
    unsigned short* h2b = (unsigned short*)w;  // n*16*2

    k_hist   <<<NP, TPB, 0, stream>>>(dst, histT, E, nbkt);
    k_scanrow<<<nbkt, 512, 0, stream>>>(histT, histS, rowtot, NP);
    k_scanbkt<<<1, 512, 0, stream>>>(rowtot, bktbase, rs, nbkt, n, E);
    k_part   <<<NP, TPB, 0, stream>>>(src, dst, histT, histS, bktbase, pk, E, nbkt);
    k_part2  <<<nbkt, TPB, 0, stream>>>(pk, bktbase, ssrc, rs, dinv, n);
    k_gemm1  <<<(n + G1_ROWS - 1) / G1_ROWS, TPB, 0, stream>>>(x, W1, dinv, h1b, n);
    k_gagg1  <<<(n + 3) / 4, TPB, 0, stream>>>(rs, ssrc, h1b, dinv, b1, h2b, n);
    k_gagg2f <<<(n + 3) / 4, TPB, 0, stream>>>(rs, ssrc, h2b, dinv, W2, b2, out, n);
}